// Round 8
// baseline (1104.591 us; speedup 1.0000x reference)
//
#include <hip/hip_runtime.h>
#include <math.h>

#define NT 64
#define KN 48
#define TOBS 30
#define NPRED 15
#define EMB 64
#define NODE 128
#define EDGE 256
#define ATTD 64
#define CNN 512
#define GNN 1024
#define GTT 512
#define TMAX 44

typedef _Float16 f16;
typedef f16 f16x8 __attribute__((ext_vector_type(8)));
typedef f16 f16x2 __attribute__((ext_vector_type(2)));
typedef float f32x4 __attribute__((ext_vector_type(4)));

__device__ __forceinline__ float rcp_f(float x) { return __builtin_amdgcn_rcpf(x); }
__device__ __forceinline__ float sigm(float x) { return rcp_f(1.f + __expf(-x)); }
__device__ __forceinline__ float tanh_f(float x) {
  float xx = fminf(fmaxf(x, -20.f), 20.f);
  float e = __expf(-2.f * xx);
  return (1.f - e) * rcp_f(1.f + e);
}
__device__ __forceinline__ unsigned ldcoh(const unsigned* p) {
  return __hip_atomic_load(p, __ATOMIC_RELAXED, __HIP_MEMORY_SCOPE_AGENT);
}
__device__ __forceinline__ float ldcohf(const float* p) {
  unsigned u = __hip_atomic_load((const unsigned*)p, __ATOMIC_RELAXED, __HIP_MEMORY_SCOPE_AGENT);
  return __builtin_bit_cast(float, u);
}
__device__ __forceinline__ void stcoh(unsigned* p, unsigned v) {
  __hip_atomic_store(p, v, __ATOMIC_RELAXED, __HIP_MEMORY_SCOPE_AGENT);
}
__device__ __forceinline__ void stcohf(float* p, float v) {
  __hip_atomic_store((unsigned*)p, __builtin_bit_cast(unsigned, v),
                     __ATOMIC_RELAXED, __HIP_MEMORY_SCOPE_AGENT);
}
// 4 coherent dwords -> 8 f16 (little-endian pair packing)
__device__ __forceinline__ f16x8 ld_hpair4(const unsigned* p) {
  union { unsigned u4[4]; f16x8 v; } cv;
  cv.u4[0] = ldcoh(p);     cv.u4[1] = ldcoh(p + 1);
  cv.u4[2] = ldcoh(p + 2); cv.u4[3] = ldcoh(p + 3);
  return cv.v;
}
__device__ __forceinline__ float f16half(unsigned wv, int hi) {
  unsigned short s = (unsigned short)(hi ? (wv >> 16) : (wv & 0xffffu));
  return (float)__builtin_bit_cast(f16, s);
}

// ---------------- prep ----------------
// Wn: 9 K-units per (h,w) group. u=0 = virtual rank-2 unit (Pn0,Pn1,Pnb),
// u=1..8: Whh_n. Ptv: target-x rank-2 vectors. R7: also zero-fills Hglob
// (first gate_n step's partner reads hit the never-written parity buffer).
__global__ __launch_bounds__(512) void prep_kernel(
    const float* __restrict__ Wih_n, const float* __restrict__ Whh_n,
    const float* __restrict__ bih_n, const float* __restrict__ bhh_n,
    const float* __restrict__ Wih_t, const float* __restrict__ Whh_t,
    const float* __restrict__ bih_t, const float* __restrict__ bhh_t,
    const float* __restrict__ W_disp, const float* __restrict__ b_disp,
    const int* __restrict__ t_hist, const int* __restrict__ n_hist,
    f16* __restrict__ Wn, f16* __restrict__ Wt, float* __restrict__ Ptv,
    float* __restrict__ bias_n, float* __restrict__ bias_t,
    int* __restrict__ gt_arr, int* __restrict__ gn_arr, float* __restrict__ cn_arr,
    int* __restrict__ last29p, unsigned* __restrict__ flags,
    unsigned* __restrict__ Hglob)
{
  const int gid = blockIdx.x * 512 + threadIdx.x;
  const int nthr = gridDim.x * 512;
  __shared__ int sgn[TMAX + 1];

  if (gid < 2 * NT) flags[gid] = 0u;
  for (int idx = gid; idx < 2 * NT * KN * 128; idx += nthr) Hglob[idx] = 0u;

  for (int idx = gid; idx < GNN * 288; idx += nthr) {
    const int j    = idx & 7;
    const int lane = (idx >> 3) & 63;
    const int g    = (idx >> 9) & 3;
    const int r    = idx >> 11;
    const int u    = r % 9;
    const int s    = r / 9;
    const int w    = s & 7;
    const int h    = s >> 3;
    const int col = g * 256 + h * 128 + w * 16 + (lane & 15);
    float v = 0.f;
    if (u == 0) {
      if ((lane >> 4) == 0 && j < 3) {
        float acc = 0.f;
        for (int e = 0; e < EMB; ++e) {
          const float sel = (j == 0) ? W_disp[e * 2]
                          : (j == 1) ? W_disp[e * 2 + 1] : b_disp[e];
          acc += sel * Wih_n[col * EMB + e];
        }
        v = acc;
      }
    } else {
      const int k = (u - 1) * 32 + (lane >> 4) * 8 + j;
      v = Whh_n[col * EDGE + k];
    }
    Wn[idx] = (f16)v;
  }
  for (int idx = gid; idx < GTT * 192; idx += nthr) {
    const int j = idx & 7;
    const int col = (idx >> 3) & 511;
    const int c8 = idx >> 12;
    const int k = c8 * 8 + j;
    const float v = (k < EMB) ? Wih_t[col * EMB + k] : Whh_t[col * NODE + (k - EMB)];
    Wt[idx] = (f16)v;
  }
  for (int idx = gid; idx < 3 * GTT; idx += nthr) {
    const int sel = idx / GTT;
    const int col = idx - sel * GTT;
    float acc = 0.f;
    for (int e = 0; e < EMB; ++e) {
      const float sv = (sel == 0) ? W_disp[e * 2]
                     : (sel == 1) ? W_disp[e * 2 + 1] : b_disp[e];
      acc += sv * Wih_t[col * EMB + e];
    }
    Ptv[sel * GTT + col] = acc;
  }
  for (int idx = gid; idx < GNN; idx += nthr) bias_n[idx] = bih_n[idx] + bhh_n[idx];
  for (int idx = gid; idx < GTT; idx += nthr) bias_t[idx] = bih_t[idx] + bhh_t[idx];

  if (blockIdx.x == 0 && threadIdx.x < 352) {
    const int t = (threadIdx.x >> 3) + 1;   // 1..44
    const int part = threadIdx.x & 7;
    int any_t = 0, cnt = 0;
    if (t < TOBS) {
      const int thr = TOBS - t;
      for (int nn = part; nn < NT; nn += 8) any_t |= (t_hist[nn] > thr) ? 1 : 0;
      for (int m = part; m < NT * KN; m += 8) cnt += (n_hist[m] > thr) ? 1 : 0;
    } else { any_t = (part == 0); cnt = (part == 0) ? NT * KN : 0; }
    #pragma unroll
    for (int off = 1; off < 8; off <<= 1) {
      any_t |= __shfl_xor(any_t, off);
      cnt   += __shfl_xor(cnt, off);
    }
    if (part == 0) {
      const int gn = (any_t && cnt > 0) ? 1 : 0;
      gt_arr[t] = any_t;
      gn_arr[t] = gn;
      cn_arr[t] = (float)cnt;
      sgn[t] = gn;
    }
  }
  __syncthreads();
  if (blockIdx.x == 0 && threadIdx.x == 0) {
    int l = 30;
    for (int t = 29; t >= 1; --t) if (sgn[t]) { l = t; break; }
    last29p[0] = l;
  }
}

// ---------------- main: TWO 512-thread blocks per target (e-halves) ----------------
// R6: rank-2 factorization (WIN, 623->525 steady).
// R7: partner-half A-fragments read DIRECTLY from Hglob (coherent 4-dword loads,
//     overlapped under own-unit MFMAs) -- the 12KB pull-to-LDS phase is deleted.
//     Ah holds own half only [KN][136] (-12KB LDS). Ht reads partner cols from
//     Hglob. hbuf tracks the parity of the last gate_n exchange (do_t-only steps
//     advance bn without Hglob writes); init hbuf=1 -> zero-filled buffer.
__global__ __launch_bounds__(512, 2) void model_kernel(
    const float* __restrict__ img, const float* __restrict__ tabs,
    const float* __restrict__ trel, const float* __restrict__ tstep,
    const float* __restrict__ nabs_g, const float* __restrict__ nstep_g,
    const int* __restrict__ thist_g, const int* __restrict__ nhist_g,
    const float* __restrict__ W_att_t, const float* __restrict__ b_att_t,
    const float* __restrict__ W_att_n, const float* __restrict__ b_att_n,
    const float* __restrict__ W_pred, const float* __restrict__ b_pred,
    const f16* __restrict__ Wn, const f16* __restrict__ Wt,
    const float* __restrict__ Ptv,
    const float* __restrict__ bias_n, const float* __restrict__ bias_t,
    const int* __restrict__ gt_arr, const int* __restrict__ gn_arr,
    const float* __restrict__ cn_arr, const int* __restrict__ last29p,
    unsigned* __restrict__ flags, unsigned* __restrict__ Hglob,
    float* __restrict__ Tglob,
    float* __restrict__ out)
{
  __shared__ f16 s_wlds[3 * 16384];   // u 0..2: [u][w][g][lane][8] = 96KB
  __shared__ f16 s_virt[KN][32];      // virtual-unit A rows: [s0,s1,1,0...]
  __shared__ f16 Ah[KN][136];         // OWN half h only (128 + 8 pad)
  __shared__ float s_tht[NODE];
  __shared__ float s_tct[64];
  __shared__ f16  s_th16[NODE];
  __shared__ float s_Ht[EDGE];
  __shared__ float s_g[256];
  __shared__ float s_bt[256];
  __shared__ float s_sc[KN], s_w[KN];
  __shared__ float s_scal[8];
  __shared__ float s_dd[4];
  __shared__ float s_pimg[2];
  __shared__ int   s_nh[KN];
  __shared__ float s_wp[2][384];
  __shared__ float s_wan0[ATTD], s_wan1[ATTD], s_ban[ATTD];
  __shared__ float s_wat0[ATTD], s_wat1[ATTD], s_bat[ATTD];

  const int tid  = threadIdx.x;
  const int n    = blockIdx.x & 63;
  const int hb   = blockIdx.x >> 6;
  const int w    = tid >> 6;
  const int lane = tid & 63;
  const int cl   = lane & 15;
  const int kq   = lane >> 4;
  const int koff = kq * 8;

  // ---- one-time init ----
  for (int i = tid; i < KN * 136; i += 512) ((f16*)Ah)[i] = (f16)0.f;
  for (int i = tid; i < KN * 32; i += 512)
    s_virt[i >> 5][i & 31] = ((i & 31) == 2) ? (f16)1.f : (f16)0.f;
  for (int i = tid; i < NODE; i += 512) { s_tht[i] = 0.f; s_th16[i] = (f16)0.f; }
  if (tid < 64) s_tct[tid] = 0.f;
  for (int i = tid; i < EDGE; i += 512) s_Ht[i] = 0.f;
  if (tid < 256) {
    const int g = tid >> 6, dl = tid & 63;
    s_bt[tid] = bias_t[g * 128 + hb * 64 + dl];
  }
  for (int i = tid; i < 768; i += 512) {
    const int ww = i / 384, j = i - ww * 384;
    s_wp[ww][j] = (j < 128) ? W_pred[ww * 896 + j] : W_pred[ww * 896 + 640 + (j - 128)];
  }
  if (tid < KN) s_nh[tid] = nhist_g[n * KN + tid];
  if (tid < 8) s_scal[tid] = 0.f;
  if (tid >= 64 && tid < 128) {
    const int a = tid - 64;
    s_wan0[a] = W_att_n[a * 2]; s_wan1[a] = W_att_n[a * 2 + 1]; s_ban[a] = b_att_n[a];
  }
  if (tid >= 128 && tid < 192) {
    const int a = tid - 128;
    s_wat0[a] = W_att_t[a * 2]; s_wat1[a] = W_att_t[a * 2 + 1]; s_bat[a] = b_att_t[a];
  }
  const int thist = thist_g[n];
  const int last29 = last29p[0];

  float pt0 = 0.f, pt1 = 0.f, ptb = 0.f;
  if (tid < 256) {
    const int col = (tid >> 6) * 128 + hb * 64 + (tid & 63);
    pt0 = Ptv[col]; pt1 = Ptv[512 + col]; ptb = Ptv[1024 + col];
  }

  // LDS-resident weight units u=0..2 (block's own slice)
  for (int i = tid; i < 3 * 8 * 256; i += 512) {
    const int c  = i & 255;
    const int wv = (i >> 8) & 7;
    const int u  = i >> 11;
    const size_t gbase = ((size_t)((hb * 8 + wv) * 9 + u)) * 2048;
    *(f16x8*)(s_wlds + (size_t)(u * 8 + wv) * 2048 + c * 8) =
        *(const f16x8*)(Wn + gbase + c * 8);
  }

  if (w < 2) {
    float s = 0.f;
    for (int j = lane; j < CNN; j += 64) s += img[n * CNN + j] * W_pred[w * 896 + 128 + j];
    for (int off = 32; off; off >>= 1) s += __shfl_down(s, off);
    if (lane == 0) s_pimg[w] = s + b_pred[w];
  }

  float creg[3][4];
  #pragma unroll
  for (int b = 0; b < 3; ++b)
    #pragma unroll
    for (int c = 0; c < 4; ++c) creg[b][c] = 0.f;

  float bias_q[4];
  #pragma unroll
  for (int g = 0; g < 4; ++g) bias_q[g] = bias_n[g * 256 + hb * 128 + w * 16 + cl];

  const f16* gW = Wn + ((size_t)(hb * 8 + w) * 9) * 2048 + (size_t)lane * 8;
  const f16* lW = s_wlds + (size_t)w * 2048 + (size_t)lane * 8;   // + u*16384 + g*512
  const int own_u0 = 1 + hb * 4;       // own-half Whh units: own_u0 .. own_u0+3
  const int lcol = w * 16 + cl;        // own-half local column of e_g
  unsigned* myflag = flags + n * 2 + hb;
  unsigned* otflag = flags + n * 2 + (1 - hb);
  int bn = 0;
  int hbuf = 1;                        // parity of last gate_n exchange (init: zeroed buf)

  __syncthreads();

  // ---- stage t=1 (obs) ----
  {
    if (tid < 96) {
      const int row = tid >> 1, comp = tid & 1;
      s_virt[row][comp] = (f16)nstep_g[((n * KN + row) * TOBS + 1) * 2 + comp];
    }
    if (tid < 2) {
      s_scal[tid]     = tabs[(n * TOBS + 1) * 2 + tid];
      s_scal[2 + tid] = trel[(n * TOBS + 1) * 2 + tid];
      s_scal[4 + tid] = tstep[(n * TOBS + 1) * 2 + tid];
    }
    if (tid >= 384 && tid < 448) {
      const int a = tid - 384;
      const float r0 = trel[(n * TOBS + 1) * 2 + 0], r1 = trel[(n * TOBS + 1) * 2 + 1];
      const float at = r0 * s_wat0[a] + r1 * s_wat1[a] + s_bat[a];
      float p0 = at * s_wan0[a], p1 = at * s_wan1[a], pb = at * s_ban[a];
      #pragma unroll
      for (int off = 32; off; off >>= 1) {
        p0 += __shfl_xor(p0, off); p1 += __shfl_xor(p1, off); pb += __shfl_xor(pb, off);
      }
      if (a == 0) { s_dd[0] = p0; s_dd[1] = p1; s_dd[2] = pb; }
    }
  }
  __syncthreads();

  for (int t = 1; t <= TMAX; ++t) {
    const bool is_obs = (t < TOBS);
    const int tc = is_obs ? t : (TOBS - 1);
    const int gate_t = gt_arr[t];
    const int gate_n = gn_arr[t];
    const float currN = cn_arr[t];
    const bool tmask = is_obs ? (thist > (TOBS - t)) : true;
    const bool do_t = gate_t && tmask;
    const bool need_x = (gate_n || do_t);
    const bool do_att = gate_n && (t >= last29);
    const int par = bn & 1;

    // ---- pred-step top: P0 + d-vector staging ----
    if (!is_obs) {
      if (w < 2) {
        float s = 0.f;
        for (int j = lane; j < NODE; j += 64) s += s_tht[j] * s_wp[w][j];
        for (int j = lane; j < EDGE; j += 64) s += s_Ht[j] * s_wp[w][128 + j];
        for (int off = 32; off; off >>= 1) s += __shfl_down(s, off);
        if (lane == 0) {
          const float p = s + s_pimg[w];
          const float cabs = s_scal[w] + p;
          const float crel = s_scal[2 + w] + p;
          s_scal[w] = cabs; s_scal[2 + w] = crel; s_scal[4 + w] = p;
          if (hb == 0) out[(n * NPRED + (t - TOBS)) * 2 + w] = crel;
        }
      }
      __syncthreads();  // A
      if (tid >= 384 && tid < 448) {
        const int a = tid - 384;
        const float at = s_scal[2] * s_wat0[a] + s_scal[3] * s_wat1[a] + s_bat[a];
        float p0 = at * s_wan0[a], p1 = at * s_wan1[a], pb = at * s_ban[a];
        #pragma unroll
        for (int off = 32; off; off >>= 1) {
          p0 += __shfl_xor(p0, off); p1 += __shfl_xor(p1, off); pb += __shfl_xor(pb, off);
        }
        if (a == 0) { s_dd[0] = p0; s_dd[1] = p1; s_dd[2] = pb; }
      }
      __syncthreads();  // B
    }

    // ---- P2: nearby LSTM via MFMA; A: virt / own-LDS / partner-global ----
    f16 hreg[3][4];
    if (gate_n) {
      const unsigned* Hgp = Hglob + (size_t)(hbuf * NT + n) * (KN * 128);
      f32x4 acc[3][4];
      #pragma unroll
      for (int rt = 0; rt < 3; ++rt)
        #pragma unroll
        for (int g = 0; g < 4; ++g) acc[rt][g] = (f32x4){0.f, 0.f, 0.f, 0.f};

      #pragma unroll
      for (int u = 0; u < 9; ++u) {
        f16x8 bf[4];
        if (u < 3) {
          #pragma unroll
          for (int g = 0; g < 4; ++g)
            bf[g] = *(const f16x8*)(lW + u * 16384 + g * 512);
        } else {
          #pragma unroll
          for (int g = 0; g < 4; ++g)
            bf[g] = *(const f16x8*)(gW + u * 2048 + g * 512);
        }
        f16x8 af[3];
        #pragma unroll
        for (int rt = 0; rt < 3; ++rt) {
          const int row = rt * 16 + cl;
          if (u == 0) {
            af[rt] = *(const f16x8*)&s_virt[row][koff];
          } else if (u >= own_u0 && u < own_u0 + 4) {
            af[rt] = *(const f16x8*)&Ah[row][(u - own_u0) * 32 + koff];
          } else {
            af[rt] = ld_hpair4(Hgp + row * 128 + (u - 1) * 16 + kq * 4);
          }
        }
        #pragma unroll
        for (int g = 0; g < 4; ++g)
          #pragma unroll
          for (int rt = 0; rt < 3; ++rt)
            acc[rt][g] = __builtin_amdgcn_mfma_f32_16x16x32_f16(af[rt], bf[g], acc[rt][g], 0, 0, 0);
      }

      unsigned* Hg = Hglob + (size_t)(par * NT + n) * (KN * 128);
      #pragma unroll
      for (int rt = 0; rt < 3; ++rt) {
        #pragma unroll
        for (int jj = 0; jj < 4; ++jj) {
          const int row = rt * 16 + kq * 4 + jj;
          const bool nm = is_obs ? (s_nh[row] > (TOBS - t)) : true;
          f16 hv;
          if (nm) {
            const float iv = acc[rt][0][jj] + bias_q[0];
            const float fv = acc[rt][1][jj] + bias_q[1];
            const float gv = acc[rt][2][jj] + bias_q[2];
            const float ov = acc[rt][3][jj] + bias_q[3];
            const float c2 = sigm(fv) * creg[rt][jj] + sigm(iv) * tanh_f(gv);
            creg[rt][jj] = c2;
            hv = (f16)(sigm(ov) * tanh_f(c2));
          } else {
            hv = Ah[row][lcol];
          }
          hreg[rt][jj] = hv;
          const unsigned lo = (unsigned)__builtin_bit_cast(unsigned short, hv);
          const unsigned hi = (unsigned)__shfl_down((int)lo, 1);
          if (!(cl & 1))
            stcoh(Hg + row * 128 + ((hb * 128 + lcol) >> 1), lo | (hi << 16));
        }
      }
    }

    // ---- target gate dots: f32 rank-2 x-part + f16 h-part (4 fdot2 chains) ----
    if (do_t && tid < 256) {
      float g0 = s_bt[tid] + s_scal[4] * pt0 + s_scal[5] * pt1 + ptb;
      float g1 = 0.f, g2 = 0.f, g3 = 0.f;
      const f16x2* th2 = (const f16x2*)s_th16;
      const f16x8* wp = (const f16x8*)(Wt + ((tid >> 6) * 128 + hb * 64 + (tid & 63)) * 8);
      #pragma unroll
      for (int c8 = 0; c8 < 16; ++c8) {
        const f16x8 wv = wp[(c8 + 8) * 512];
        f16x2 w0 = {wv[0], wv[1]}, w1 = {wv[2], wv[3]};
        f16x2 w2 = {wv[4], wv[5]}, w3 = {wv[6], wv[7]};
        g0 = __builtin_amdgcn_fdot2(w0, th2[c8 * 4 + 0], g0, false);
        g1 = __builtin_amdgcn_fdot2(w1, th2[c8 * 4 + 1], g1, false);
        g2 = __builtin_amdgcn_fdot2(w2, th2[c8 * 4 + 2], g2, false);
        g3 = __builtin_amdgcn_fdot2(w3, th2[c8 * 4 + 3], g3, false);
      }
      s_g[tid] = (g0 + g1) + (g2 + g3);
    }
    // ---- attention scores via d-vectors (rank-2) ----
    if (do_att && tid >= 256 && tid < 256 + KN) {
      const int k = tid - 256;
      const float a0 = nabs_g[((n * KN + k) * TOBS + tc) * 2 + 0] - s_scal[0];
      const float a1 = nabs_g[((n * KN + k) * TOBS + tc) * 2 + 1] - s_scal[1];
      const bool nm = is_obs ? (s_nh[k] > (TOBS - t)) : true;
      const float sc = (a0 * s_dd[0] + a1 * s_dd[1] + s_dd[2]) * currN * 0.125f;
      s_sc[k] = nm ? sc : 0.f;
      s_w[k]  = nm ? 1.f : 0.f;
    }
    __syncthreads();  // C1

    // ---- cell update + publish; softmax ----
    if (do_t && tid < 64) {
      const int d = hb * 64 + tid;
      const float iv = s_g[tid], fv = s_g[64 + tid];
      const float gv = s_g[128 + tid], ov = s_g[192 + tid];
      const float c2 = sigm(fv) * s_tct[tid] + sigm(iv) * tanh_f(gv);
      s_tct[tid] = c2;
      const float nh = sigm(ov) * tanh_f(c2);
      s_tht[d] = nh;
      s_th16[d] = (f16)nh;
      stcohf(Tglob + ((size_t)(par * NT + n) * 2 + hb) * 64 + tid, nh);
    }
    if (do_att && w == 4) {
      const bool act = lane < KN;
      const float sc = act ? s_sc[lane] : -1.0e30f;
      const float mf = act ? s_w[lane] : 0.f;
      float mx = sc;
      #pragma unroll
      for (int off = 32; off; off >>= 1) mx = fmaxf(mx, __shfl_xor(mx, off));
      float num = __expf(sc - mx) * mf;
      float sum = num;
      #pragma unroll
      for (int off = 32; off; off >>= 1) sum += __shfl_xor(sum, off);
      if (act) s_w[lane] = num * rcp_f(sum + 1e-6f);
    }
    __syncthreads();  // C2: drains all MALL stores before publish

    if (need_x && tid == 0) {
      stcoh(myflag, (unsigned)(bn + 1));   // publish
    }

    // ---- prestage t+1 (off the serial path, while partner finishes) ----
    {
      const int tn = t + 1;
      if (tn <= TOBS) {
        const int tcn = (tn < TOBS) ? tn : (TOBS - 1);
        if (tid < 96) {
          const int row = tid >> 1, comp = tid & 1;
          s_virt[row][comp] = (f16)nstep_g[((n * KN + row) * TOBS + tcn) * 2 + comp];
        }
      }
      if (tn < TOBS) {
        if (tid < 2) {
          s_scal[tid]     = tabs[(n * TOBS + tn) * 2 + tid];
          s_scal[2 + tid] = trel[(n * TOBS + tn) * 2 + tid];
          s_scal[4 + tid] = tstep[(n * TOBS + tn) * 2 + tid];
        }
        if (tid >= 384 && tid < 448) {
          const int a = tid - 384;
          const float r0 = trel[(n * TOBS + tn) * 2 + 0], r1 = trel[(n * TOBS + tn) * 2 + 1];
          const float at = r0 * s_wat0[a] + r1 * s_wat1[a] + s_bat[a];
          float p0 = at * s_wan0[a], p1 = at * s_wan1[a], pb = at * s_ban[a];
          #pragma unroll
          for (int off = 32; off; off >>= 1) {
            p0 += __shfl_xor(p0, off); p1 += __shfl_xor(p1, off); pb += __shfl_xor(pb, off);
          }
          if (a == 0) { s_dd[0] = p0; s_dd[1] = p1; s_dd[2] = pb; }
        }
      }
    }

    if (need_x && tid == 0) {
      const unsigned step = (unsigned)(bn + 1);
      while (ldcoh(otflag) < step)
        __builtin_amdgcn_s_sleep(1);
    }
    __syncthreads();  // D

    // ---- own-half h -> Ah (no partner pull; partner read direct next step) ----
    if (gate_n) {
      #pragma unroll
      for (int rt = 0; rt < 3; ++rt)
        #pragma unroll
        for (int jj = 0; jj < 4; ++jj)
          Ah[rt * 16 + kq * 4 + jj][lcol] = hreg[rt][jj];
      hbuf = par;   // this exchange's buffer holds the latest h
    }
    if (do_t && tid >= 448) {
      const int dl = tid - 448;
      const int d = (1 - hb) * 64 + dl;
      const float nh = ldcohf(Tglob + ((size_t)(par * NT + n) * 2 + (1 - hb)) * 64 + dl);
      s_tht[d] = nh;
      s_th16[d] = (f16)nh;
    }
    __syncthreads();  // E

    // ---- Ht (only t >= last29): own cols from Ah, partner cols from Hglob ----
    if (do_att && tid < EDGE) {
      const bool ownh = ((tid >> 7) == hb);
      const unsigned* Hgc = Hglob + (size_t)(par * NT + n) * (KN * 128) + (tid >> 1);
      const int hi16 = tid & 1;
      const int lc = tid & 127;
      float h0 = 0.f, h1 = 0.f, h2 = 0.f, h3 = 0.f;
      if (ownh) {
        #pragma unroll
        for (int k = 0; k < KN; k += 4) {
          h0 += (float)Ah[k][lc]     * s_w[k];
          h1 += (float)Ah[k + 1][lc] * s_w[k + 1];
          h2 += (float)Ah[k + 2][lc] * s_w[k + 2];
          h3 += (float)Ah[k + 3][lc] * s_w[k + 3];
        }
      } else {
        #pragma unroll
        for (int k = 0; k < KN; k += 4) {
          h0 += f16half(ldcoh(Hgc + (k)     * 128), hi16) * s_w[k];
          h1 += f16half(ldcoh(Hgc + (k + 1) * 128), hi16) * s_w[k + 1];
          h2 += f16half(ldcoh(Hgc + (k + 2) * 128), hi16) * s_w[k + 2];
          h3 += f16half(ldcoh(Hgc + (k + 3) * 128), hi16) * s_w[k + 3];
        }
      }
      s_Ht[tid] = (h0 + h1) + (h2 + h3);
    }
    if (need_x) bn++;
    if (t >= 29) __syncthreads();  // F: only needed before pred P0 reads s_Ht
  }
}

extern "C" void kernel_launch(void* const* d_in, const int* in_sizes, int n_in,
                              void* d_out, int out_size, void* d_ws, size_t ws_size,
                              hipStream_t stream) {
  const float* img    = (const float*)d_in[0];
  const float* tabs   = (const float*)d_in[1];
  const float* trel   = (const float*)d_in[2];
  const float* tstep  = (const float*)d_in[3];
  const float* nabs   = (const float*)d_in[4];
  const float* nstep  = (const float*)d_in[6];
  const int*   thist  = (const int*)d_in[7];
  const int*   nhist  = (const int*)d_in[8];
  const float* W_disp = (const float*)d_in[9];
  const float* b_disp = (const float*)d_in[10];
  const float* Wih_t  = (const float*)d_in[11];
  const float* Whh_t  = (const float*)d_in[12];
  const float* bih_t  = (const float*)d_in[13];
  const float* bhh_t  = (const float*)d_in[14];
  const float* Wih_n  = (const float*)d_in[15];
  const float* Whh_n  = (const float*)d_in[16];
  const float* bih_n  = (const float*)d_in[17];
  const float* bhh_n  = (const float*)d_in[18];
  const float* W_att_t = (const float*)d_in[19];
  const float* b_att_t = (const float*)d_in[20];
  const float* W_att_n = (const float*)d_in[21];
  const float* b_att_n = (const float*)d_in[22];
  const float* W_pred  = (const float*)d_in[23];
  const float* b_pred  = (const float*)d_in[24];

  char* ws = (char*)d_ws;
  f16*      Wn      = (f16*)(ws);              // 589824 B (9-unit layout)
  f16*      Wt      = (f16*)(ws + 655360);     // 196608 B
  float*    bias_n  = (float*)(ws + 851968);
  float*    bias_t  = (float*)(ws + 856064);
  int*      gt_arr  = (int*)(ws + 858112);
  int*      gn_arr  = (int*)(ws + 858304);
  float*    cn_arr  = (float*)(ws + 858496);
  int*      last29p = (int*)(ws + 859648);
  unsigned* flags   = (unsigned*)(ws + 860160);
  float*    Ptv     = (float*)(ws + 901120);      // 3*512 f32 = 6144 B
  unsigned* Hglob   = (unsigned*)(ws + 1048576);  // 3145728 B
  float*    Tglob   = (float*)(ws + 4194304);     // 131072 B

  prep_kernel<<<64, 512, 0, stream>>>(Wih_n, Whh_n, bih_n, bhh_n, Wih_t, Whh_t,
                                      bih_t, bhh_t, W_disp, b_disp,
                                      thist, nhist, Wn, Wt, Ptv,
                                      bias_n, bias_t, gt_arr, gn_arr, cn_arr,
                                      last29p, flags, Hglob);
  model_kernel<<<2 * NT, 512, 0, stream>>>(img, tabs, trel, tstep, nabs, nstep,
                                           thist, nhist,
                                           W_att_t, b_att_t, W_att_n, b_att_n,
                                           W_pred, b_pred,
                                           Wn, Wt, Ptv, bias_n, bias_t,
                                           gt_arr, gn_arr, cn_arr, last29p,
                                           flags, Hglob, Tglob,
                                           (float*)d_out);
}

// Round 10
// 588.615 us; speedup vs baseline: 1.8766x; 1.8766x over previous
//
#include <hip/hip_runtime.h>
#include <math.h>

#define NT 64
#define KN 48
#define TOBS 30
#define NPRED 15
#define EMB 64
#define NODE 128
#define EDGE 256
#define ATTD 64
#define CNN 512
#define GNN 1024
#define GTT 512
#define TMAX 44

typedef _Float16 f16;
typedef f16 f16x8 __attribute__((ext_vector_type(8)));
typedef f16 f16x2 __attribute__((ext_vector_type(2)));
typedef float f32x4 __attribute__((ext_vector_type(4)));

__device__ __forceinline__ float rcp_f(float x) { return __builtin_amdgcn_rcpf(x); }
__device__ __forceinline__ float sigm(float x) { return rcp_f(1.f + __expf(-x)); }
__device__ __forceinline__ float tanh_f(float x) {
  float xx = fminf(fmaxf(x, -20.f), 20.f);
  float e = __expf(-2.f * xx);
  return (1.f - e) * rcp_f(1.f + e);
}
__device__ __forceinline__ unsigned ldcoh(const unsigned* p) {
  return __hip_atomic_load(p, __ATOMIC_RELAXED, __HIP_MEMORY_SCOPE_AGENT);
}
__device__ __forceinline__ unsigned long long ldcoh8(const unsigned long long* p) {
  return __hip_atomic_load(p, __ATOMIC_RELAXED, __HIP_MEMORY_SCOPE_AGENT);
}
__device__ __forceinline__ float ldcohf(const float* p) {
  unsigned u = __hip_atomic_load((const unsigned*)p, __ATOMIC_RELAXED, __HIP_MEMORY_SCOPE_AGENT);
  return __builtin_bit_cast(float, u);
}
__device__ __forceinline__ void stcoh(unsigned* p, unsigned v) {
  __hip_atomic_store(p, v, __ATOMIC_RELAXED, __HIP_MEMORY_SCOPE_AGENT);
}
__device__ __forceinline__ void stcohf(float* p, float v) {
  __hip_atomic_store((unsigned*)p, __builtin_bit_cast(unsigned, v),
                     __ATOMIC_RELAXED, __HIP_MEMORY_SCOPE_AGENT);
}

// ---------------- prep ----------------
// Wn: 9 K-units per (h,w) group. u=0 = virtual rank-2 unit (Pn0,Pn1,Pnb),
// u=1..8: Whh_n. Ptv: target-x rank-2 vectors.
__global__ __launch_bounds__(512) void prep_kernel(
    const float* __restrict__ Wih_n, const float* __restrict__ Whh_n,
    const float* __restrict__ bih_n, const float* __restrict__ bhh_n,
    const float* __restrict__ Wih_t, const float* __restrict__ Whh_t,
    const float* __restrict__ bih_t, const float* __restrict__ bhh_t,
    const float* __restrict__ W_disp, const float* __restrict__ b_disp,
    const int* __restrict__ t_hist, const int* __restrict__ n_hist,
    f16* __restrict__ Wn, f16* __restrict__ Wt, float* __restrict__ Ptv,
    float* __restrict__ bias_n, float* __restrict__ bias_t,
    int* __restrict__ gt_arr, int* __restrict__ gn_arr, float* __restrict__ cn_arr,
    int* __restrict__ last29p, unsigned* __restrict__ flags)
{
  const int gid = blockIdx.x * 512 + threadIdx.x;
  const int nthr = gridDim.x * 512;
  __shared__ int sgn[TMAX + 1];

  if (gid < 2 * NT) flags[gid] = 0u;

  for (int idx = gid; idx < GNN * 288; idx += nthr) {
    const int j    = idx & 7;
    const int lane = (idx >> 3) & 63;
    const int g    = (idx >> 9) & 3;
    const int r    = idx >> 11;
    const int u    = r % 9;
    const int s    = r / 9;
    const int w    = s & 7;
    const int h    = s >> 3;
    const int col = g * 256 + h * 128 + w * 16 + (lane & 15);
    float v = 0.f;
    if (u == 0) {
      if ((lane >> 4) == 0 && j < 3) {
        float acc = 0.f;
        for (int e = 0; e < EMB; ++e) {
          const float sel = (j == 0) ? W_disp[e * 2]
                          : (j == 1) ? W_disp[e * 2 + 1] : b_disp[e];
          acc += sel * Wih_n[col * EMB + e];
        }
        v = acc;
      }
    } else {
      const int k = (u - 1) * 32 + (lane >> 4) * 8 + j;
      v = Whh_n[col * EDGE + k];
    }
    Wn[idx] = (f16)v;
  }
  for (int idx = gid; idx < GTT * 192; idx += nthr) {
    const int j = idx & 7;
    const int col = (idx >> 3) & 511;
    const int c8 = idx >> 12;
    const int k = c8 * 8 + j;
    const float v = (k < EMB) ? Wih_t[col * EMB + k] : Whh_t[col * NODE + (k - EMB)];
    Wt[idx] = (f16)v;
  }
  for (int idx = gid; idx < 3 * GTT; idx += nthr) {
    const int sel = idx / GTT;
    const int col = idx - sel * GTT;
    float acc = 0.f;
    for (int e = 0; e < EMB; ++e) {
      const float sv = (sel == 0) ? W_disp[e * 2]
                     : (sel == 1) ? W_disp[e * 2 + 1] : b_disp[e];
      acc += sv * Wih_t[col * EMB + e];
    }
    Ptv[sel * GTT + col] = acc;
  }
  for (int idx = gid; idx < GNN; idx += nthr) bias_n[idx] = bih_n[idx] + bhh_n[idx];
  for (int idx = gid; idx < GTT; idx += nthr) bias_t[idx] = bih_t[idx] + bhh_t[idx];

  if (blockIdx.x == 0 && threadIdx.x < 352) {
    const int t = (threadIdx.x >> 3) + 1;   // 1..44
    const int part = threadIdx.x & 7;
    int any_t = 0, cnt = 0;
    if (t < TOBS) {
      const int thr = TOBS - t;
      for (int nn = part; nn < NT; nn += 8) any_t |= (t_hist[nn] > thr) ? 1 : 0;
      for (int m = part; m < NT * KN; m += 8) cnt += (n_hist[m] > thr) ? 1 : 0;
    } else { any_t = (part == 0); cnt = (part == 0) ? NT * KN : 0; }
    #pragma unroll
    for (int off = 1; off < 8; off <<= 1) {
      any_t |= __shfl_xor(any_t, off);
      cnt   += __shfl_xor(cnt, off);
    }
    if (part == 0) {
      const int gn = (any_t && cnt > 0) ? 1 : 0;
      gt_arr[t] = any_t;
      gn_arr[t] = gn;
      cn_arr[t] = (float)cnt;
      sgn[t] = gn;
    }
  }
  __syncthreads();
  if (blockIdx.x == 0 && threadIdx.x == 0) {
    int l = 30;
    for (int t = 29; t >= 1; --t) if (sgn[t]) { l = t; break; }
    last29p[0] = l;
  }
}

// ---------------- main: TWO 512-thread blocks per target (e-halves) ----------------
// R6: rank-2 factorization (WIN, 623->525 steady). R7 (partner reads strewn
// through MFMA phase as scalar atomics): +90% REGRESSION -- coherent MALL reads
// must be batched+decoupled, never on the compute critical path. Reverted.
// R8 = R6 + (a) partner pull via b64 atomic loads (3/thread, was 6 b32),
//          (b) own-hreg->Ah writeback moved off the serial path (post-publish,
//              pre-poll; Ah unread between C1 and E so this is order-safe).
// R9: resubmitted unchanged (GPU unavailable in R9).
__global__ __launch_bounds__(512, 2) void model_kernel(
    const float* __restrict__ img, const float* __restrict__ tabs,
    const float* __restrict__ trel, const float* __restrict__ tstep,
    const float* __restrict__ nabs_g, const float* __restrict__ nstep_g,
    const int* __restrict__ thist_g, const int* __restrict__ nhist_g,
    const float* __restrict__ W_att_t, const float* __restrict__ b_att_t,
    const float* __restrict__ W_att_n, const float* __restrict__ b_att_n,
    const float* __restrict__ W_pred, const float* __restrict__ b_pred,
    const f16* __restrict__ Wn, const f16* __restrict__ Wt,
    const float* __restrict__ Ptv,
    const float* __restrict__ bias_n, const float* __restrict__ bias_t,
    const int* __restrict__ gt_arr, const int* __restrict__ gn_arr,
    const float* __restrict__ cn_arr, const int* __restrict__ last29p,
    unsigned* __restrict__ flags, unsigned* __restrict__ Hglob,
    float* __restrict__ Tglob,
    float* __restrict__ out)
{
  __shared__ f16 s_wlds[3 * 16384];   // u 0..2: [u][w][g][lane][8] = 96KB
  __shared__ f16 s_virt[KN][32];      // virtual-unit A rows: [s0,s1,1,0...]
  __shared__ f16 Ah[KN][264];
  __shared__ float s_tht[NODE];
  __shared__ float s_tct[64];
  __shared__ f16  s_th16[NODE];
  __shared__ float s_Ht[EDGE];
  __shared__ float s_g[256];
  __shared__ float s_bt[256];
  __shared__ float s_sc[KN], s_w[KN];
  __shared__ float s_scal[8];
  __shared__ float s_dd[4];
  __shared__ float s_pimg[2];
  __shared__ int   s_nh[KN];
  __shared__ float s_wp[2][384];
  __shared__ float s_wan0[ATTD], s_wan1[ATTD], s_ban[ATTD];
  __shared__ float s_wat0[ATTD], s_wat1[ATTD], s_bat[ATTD];

  const int tid  = threadIdx.x;
  const int n    = blockIdx.x & 63;
  const int hb   = blockIdx.x >> 6;
  const int w    = tid >> 6;
  const int lane = tid & 63;
  const int cl   = lane & 15;
  const int kq   = lane >> 4;
  const int koff = kq * 8;

  // ---- one-time init ----
  for (int i = tid; i < KN * 264; i += 512) ((f16*)Ah)[i] = (f16)0.f;
  for (int i = tid; i < KN * 32; i += 512)
    s_virt[i >> 5][i & 31] = ((i & 31) == 2) ? (f16)1.f : (f16)0.f;
  for (int i = tid; i < NODE; i += 512) { s_tht[i] = 0.f; s_th16[i] = (f16)0.f; }
  if (tid < 64) s_tct[tid] = 0.f;
  for (int i = tid; i < EDGE; i += 512) s_Ht[i] = 0.f;
  if (tid < 256) {
    const int g = tid >> 6, dl = tid & 63;
    s_bt[tid] = bias_t[g * 128 + hb * 64 + dl];
  }
  for (int i = tid; i < 768; i += 512) {
    const int ww = i / 384, j = i - ww * 384;
    s_wp[ww][j] = (j < 128) ? W_pred[ww * 896 + j] : W_pred[ww * 896 + 640 + (j - 128)];
  }
  if (tid < KN) s_nh[tid] = nhist_g[n * KN + tid];
  if (tid < 8) s_scal[tid] = 0.f;
  if (tid >= 64 && tid < 128) {
    const int a = tid - 64;
    s_wan0[a] = W_att_n[a * 2]; s_wan1[a] = W_att_n[a * 2 + 1]; s_ban[a] = b_att_n[a];
  }
  if (tid >= 128 && tid < 192) {
    const int a = tid - 128;
    s_wat0[a] = W_att_t[a * 2]; s_wat1[a] = W_att_t[a * 2 + 1]; s_bat[a] = b_att_t[a];
  }
  const int thist = thist_g[n];
  const int last29 = last29p[0];

  float pt0 = 0.f, pt1 = 0.f, ptb = 0.f;
  if (tid < 256) {
    const int col = (tid >> 6) * 128 + hb * 64 + (tid & 63);
    pt0 = Ptv[col]; pt1 = Ptv[512 + col]; ptb = Ptv[1024 + col];
  }

  // LDS-resident weight units u=0..2 (block's own slice)
  for (int i = tid; i < 3 * 8 * 256; i += 512) {
    const int c  = i & 255;
    const int wv = (i >> 8) & 7;
    const int u  = i >> 11;
    const size_t gbase = ((size_t)((hb * 8 + wv) * 9 + u)) * 2048;
    *(f16x8*)(s_wlds + (size_t)(u * 8 + wv) * 2048 + c * 8) =
        *(const f16x8*)(Wn + gbase + c * 8);
  }

  if (w < 2) {
    float s = 0.f;
    for (int j = lane; j < CNN; j += 64) s += img[n * CNN + j] * W_pred[w * 896 + 128 + j];
    for (int off = 32; off; off >>= 1) s += __shfl_down(s, off);
    if (lane == 0) s_pimg[w] = s + b_pred[w];
  }

  float creg[3][4];
  #pragma unroll
  for (int b = 0; b < 3; ++b)
    #pragma unroll
    for (int c = 0; c < 4; ++c) creg[b][c] = 0.f;

  float bias_q[4];
  #pragma unroll
  for (int g = 0; g < 4; ++g) bias_q[g] = bias_n[g * 256 + hb * 128 + w * 16 + cl];

  const f16* gW = Wn + ((size_t)(hb * 8 + w) * 9) * 2048 + (size_t)lane * 8;
  const f16* lW = s_wlds + (size_t)w * 2048 + (size_t)lane * 8;   // + u*16384 + g*512
  const int e_g = hb * 128 + w * 16 + cl;
  unsigned* myflag = flags + n * 2 + hb;
  unsigned* otflag = flags + n * 2 + (1 - hb);
  int bn = 0;

  __syncthreads();

  // ---- stage t=1 (obs) ----
  {
    if (tid < 96) {
      const int row = tid >> 1, comp = tid & 1;
      s_virt[row][comp] = (f16)nstep_g[((n * KN + row) * TOBS + 1) * 2 + comp];
    }
    if (tid < 2) {
      s_scal[tid]     = tabs[(n * TOBS + 1) * 2 + tid];
      s_scal[2 + tid] = trel[(n * TOBS + 1) * 2 + tid];
      s_scal[4 + tid] = tstep[(n * TOBS + 1) * 2 + tid];
    }
    if (tid >= 384 && tid < 448) {
      const int a = tid - 384;
      const float r0 = trel[(n * TOBS + 1) * 2 + 0], r1 = trel[(n * TOBS + 1) * 2 + 1];
      const float at = r0 * s_wat0[a] + r1 * s_wat1[a] + s_bat[a];
      float p0 = at * s_wan0[a], p1 = at * s_wan1[a], pb = at * s_ban[a];
      #pragma unroll
      for (int off = 32; off; off >>= 1) {
        p0 += __shfl_xor(p0, off); p1 += __shfl_xor(p1, off); pb += __shfl_xor(pb, off);
      }
      if (a == 0) { s_dd[0] = p0; s_dd[1] = p1; s_dd[2] = pb; }
    }
  }
  __syncthreads();

  for (int t = 1; t <= TMAX; ++t) {
    const bool is_obs = (t < TOBS);
    const int tc = is_obs ? t : (TOBS - 1);
    const int gate_t = gt_arr[t];
    const int gate_n = gn_arr[t];
    const float currN = cn_arr[t];
    const bool tmask = is_obs ? (thist > (TOBS - t)) : true;
    const bool do_t = gate_t && tmask;
    const bool need_x = (gate_n || do_t);
    const bool do_att = gate_n && (t >= last29);
    const int par = bn & 1;

    // ---- pred-step top: P0 + d-vector staging ----
    if (!is_obs) {
      if (w < 2) {
        float s = 0.f;
        for (int j = lane; j < NODE; j += 64) s += s_tht[j] * s_wp[w][j];
        for (int j = lane; j < EDGE; j += 64) s += s_Ht[j] * s_wp[w][128 + j];
        for (int off = 32; off; off >>= 1) s += __shfl_down(s, off);
        if (lane == 0) {
          const float p = s + s_pimg[w];
          const float cabs = s_scal[w] + p;
          const float crel = s_scal[2 + w] + p;
          s_scal[w] = cabs; s_scal[2 + w] = crel; s_scal[4 + w] = p;
          if (hb == 0) out[(n * NPRED + (t - TOBS)) * 2 + w] = crel;
        }
      }
      __syncthreads();  // A
      if (tid >= 384 && tid < 448) {
        const int a = tid - 384;
        const float at = s_scal[2] * s_wat0[a] + s_scal[3] * s_wat1[a] + s_bat[a];
        float p0 = at * s_wan0[a], p1 = at * s_wan1[a], pb = at * s_ban[a];
        #pragma unroll
        for (int off = 32; off; off >>= 1) {
          p0 += __shfl_xor(p0, off); p1 += __shfl_xor(p1, off); pb += __shfl_xor(pb, off);
        }
        if (a == 0) { s_dd[0] = p0; s_dd[1] = p1; s_dd[2] = pb; }
      }
      __syncthreads();  // B
    }

    // ---- P2: nearby LSTM via MFMA; u=0 virtual rank-2 unit, u=1..8 Whh ----
    f16 hreg[3][4];
    if (gate_n) {
      f32x4 acc[3][4];
      #pragma unroll
      for (int rt = 0; rt < 3; ++rt)
        #pragma unroll
        for (int g = 0; g < 4; ++g) acc[rt][g] = (f32x4){0.f, 0.f, 0.f, 0.f};

      #pragma unroll
      for (int u = 0; u < 9; ++u) {
        f16x8 bf[4];
        if (u < 3) {
          #pragma unroll
          for (int g = 0; g < 4; ++g)
            bf[g] = *(const f16x8*)(lW + u * 16384 + g * 512);
        } else {
          #pragma unroll
          for (int g = 0; g < 4; ++g)
            bf[g] = *(const f16x8*)(gW + u * 2048 + g * 512);
        }
        f16x8 af[3];
        #pragma unroll
        for (int rt = 0; rt < 3; ++rt) {
          const int row = rt * 16 + cl;
          const f16* ap = (u == 0) ? &s_virt[row][koff]
                                   : &Ah[row][(u - 1) * 32 + koff];
          af[rt] = *(const f16x8*)ap;
        }
        #pragma unroll
        for (int g = 0; g < 4; ++g)
          #pragma unroll
          for (int rt = 0; rt < 3; ++rt)
            acc[rt][g] = __builtin_amdgcn_mfma_f32_16x16x32_f16(af[rt], bf[g], acc[rt][g], 0, 0, 0);
      }

      unsigned* Hg = Hglob + (size_t)(par * NT + n) * (KN * 128);
      #pragma unroll
      for (int rt = 0; rt < 3; ++rt) {
        #pragma unroll
        for (int jj = 0; jj < 4; ++jj) {
          const int row = rt * 16 + kq * 4 + jj;
          const bool nm = is_obs ? (s_nh[row] > (TOBS - t)) : true;
          f16 hv;
          if (nm) {
            const float iv = acc[rt][0][jj] + bias_q[0];
            const float fv = acc[rt][1][jj] + bias_q[1];
            const float gv = acc[rt][2][jj] + bias_q[2];
            const float ov = acc[rt][3][jj] + bias_q[3];
            const float c2 = sigm(fv) * creg[rt][jj] + sigm(iv) * tanh_f(gv);
            creg[rt][jj] = c2;
            hv = (f16)(sigm(ov) * tanh_f(c2));
          } else {
            hv = Ah[row][e_g];
          }
          hreg[rt][jj] = hv;
          const unsigned lo = (unsigned)__builtin_bit_cast(unsigned short, hv);
          const unsigned hi = (unsigned)__shfl_down((int)lo, 1);
          if (!(cl & 1))
            stcoh(Hg + row * 128 + (e_g >> 1), lo | (hi << 16));
        }
      }
    }

    // ---- target gate dots: f32 rank-2 x-part + f16 h-part (4 fdot2 chains) ----
    if (do_t && tid < 256) {
      float g0 = s_bt[tid] + s_scal[4] * pt0 + s_scal[5] * pt1 + ptb;
      float g1 = 0.f, g2 = 0.f, g3 = 0.f;
      const f16x2* th2 = (const f16x2*)s_th16;
      const f16x8* wp = (const f16x8*)(Wt + ((tid >> 6) * 128 + hb * 64 + (tid & 63)) * 8);
      #pragma unroll
      for (int c8 = 0; c8 < 16; ++c8) {
        const f16x8 wv = wp[(c8 + 8) * 512];
        f16x2 w0 = {wv[0], wv[1]}, w1 = {wv[2], wv[3]};
        f16x2 w2 = {wv[4], wv[5]}, w3 = {wv[6], wv[7]};
        g0 = __builtin_amdgcn_fdot2(w0, th2[c8 * 4 + 0], g0, false);
        g1 = __builtin_amdgcn_fdot2(w1, th2[c8 * 4 + 1], g1, false);
        g2 = __builtin_amdgcn_fdot2(w2, th2[c8 * 4 + 2], g2, false);
        g3 = __builtin_amdgcn_fdot2(w3, th2[c8 * 4 + 3], g3, false);
      }
      s_g[tid] = (g0 + g1) + (g2 + g3);
    }
    // ---- attention scores via d-vectors (rank-2) ----
    if (do_att && tid >= 256 && tid < 256 + KN) {
      const int k = tid - 256;
      const float a0 = nabs_g[((n * KN + k) * TOBS + tc) * 2 + 0] - s_scal[0];
      const float a1 = nabs_g[((n * KN + k) * TOBS + tc) * 2 + 1] - s_scal[1];
      const bool nm = is_obs ? (s_nh[k] > (TOBS - t)) : true;
      const float sc = (a0 * s_dd[0] + a1 * s_dd[1] + s_dd[2]) * currN * 0.125f;
      s_sc[k] = nm ? sc : 0.f;
      s_w[k]  = nm ? 1.f : 0.f;
    }
    __syncthreads();  // C1

    // ---- cell update + publish; softmax ----
    if (do_t && tid < 64) {
      const int d = hb * 64 + tid;
      const float iv = s_g[tid], fv = s_g[64 + tid];
      const float gv = s_g[128 + tid], ov = s_g[192 + tid];
      const float c2 = sigm(fv) * s_tct[tid] + sigm(iv) * tanh_f(gv);
      s_tct[tid] = c2;
      const float nh = sigm(ov) * tanh_f(c2);
      s_tht[d] = nh;
      s_th16[d] = (f16)nh;
      stcohf(Tglob + ((size_t)(par * NT + n) * 2 + hb) * 64 + tid, nh);
    }
    if (do_att && w == 4) {
      const bool act = lane < KN;
      const float sc = act ? s_sc[lane] : -1.0e30f;
      const float mf = act ? s_w[lane] : 0.f;
      float mx = sc;
      #pragma unroll
      for (int off = 32; off; off >>= 1) mx = fmaxf(mx, __shfl_xor(mx, off));
      float num = __expf(sc - mx) * mf;
      float sum = num;
      #pragma unroll
      for (int off = 32; off; off >>= 1) sum += __shfl_xor(sum, off);
      if (act) s_w[lane] = num * rcp_f(sum + 1e-6f);
    }
    __syncthreads();  // C2: drains all MALL stores before publish

    if (need_x && tid == 0) {
      stcoh(myflag, (unsigned)(bn + 1));   // publish
    }

    // ---- own-hreg -> Ah writeback: OFF the serial path (R8b) ----
    // Safe: Ah is not read by any wave between C1 and E; all waves passed C2.
    if (gate_n) {
      #pragma unroll
      for (int rt = 0; rt < 3; ++rt)
        #pragma unroll
        for (int jj = 0; jj < 4; ++jj)
          Ah[rt * 16 + kq * 4 + jj][e_g] = hreg[rt][jj];
    }

    // ---- prestage t+1 (off the serial path, while partner finishes) ----
    {
      const int tn = t + 1;
      if (tn <= TOBS) {
        const int tcn = (tn < TOBS) ? tn : (TOBS - 1);
        if (tid < 96) {
          const int row = tid >> 1, comp = tid & 1;
          s_virt[row][comp] = (f16)nstep_g[((n * KN + row) * TOBS + tcn) * 2 + comp];
        }
      }
      if (tn < TOBS) {
        if (tid < 2) {
          s_scal[tid]     = tabs[(n * TOBS + tn) * 2 + tid];
          s_scal[2 + tid] = trel[(n * TOBS + tn) * 2 + tid];
          s_scal[4 + tid] = tstep[(n * TOBS + tn) * 2 + tid];
        }
        if (tid >= 384 && tid < 448) {
          const int a = tid - 384;
          const float r0 = trel[(n * TOBS + tn) * 2 + 0], r1 = trel[(n * TOBS + tn) * 2 + 1];
          const float at = r0 * s_wat0[a] + r1 * s_wat1[a] + s_bat[a];
          float p0 = at * s_wan0[a], p1 = at * s_wan1[a], pb = at * s_ban[a];
          #pragma unroll
          for (int off = 32; off; off >>= 1) {
            p0 += __shfl_xor(p0, off); p1 += __shfl_xor(p1, off); pb += __shfl_xor(pb, off);
          }
          if (a == 0) { s_dd[0] = p0; s_dd[1] = p1; s_dd[2] = pb; }
        }
      }
    }

    if (need_x && tid == 0) {
      const unsigned step = (unsigned)(bn + 1);
      while (ldcoh(otflag) < step)
        __builtin_amdgcn_s_sleep(1);
    }
    __syncthreads();  // D

    // ---- pull partner half (b64 coherent loads, 3 per thread — R8a) ----
    if (gate_n) {
      const unsigned long long* Hg8 =
          (const unsigned long long*)(Hglob + (size_t)(par * NT + n) * (KN * 128));
      const int ob8 = (1 - hb) * 32;   // partner half, in 8-byte units (64 dwords)
      for (int i = tid; i < KN * 32; i += 512) {   // 3 iterations
        const int row = i >> 5, c = i & 31;
        const unsigned long long v = ldcoh8(Hg8 + row * 64 + ob8 + c);
        *(unsigned long long*)&Ah[row][((1 - hb) * 64 + c * 2) * 2] = v;
      }
    }
    if (do_t && tid >= 448) {
      const int dl = tid - 448;
      const int d = (1 - hb) * 64 + dl;
      const float nh = ldcohf(Tglob + ((size_t)(par * NT + n) * 2 + (1 - hb)) * 64 + dl);
      s_tht[d] = nh;
      s_th16[d] = (f16)nh;
    }
    __syncthreads();  // E

    // ---- Ht (only t >= last29), 4 indep chains ----
    if (do_att && tid < EDGE) {
      float h0 = 0.f, h1 = 0.f, h2 = 0.f, h3 = 0.f;
      #pragma unroll
      for (int k = 0; k < KN; k += 4) {
        h0 += (float)Ah[k][tid]     * s_w[k];
        h1 += (float)Ah[k + 1][tid] * s_w[k + 1];
        h2 += (float)Ah[k + 2][tid] * s_w[k + 2];
        h3 += (float)Ah[k + 3][tid] * s_w[k + 3];
      }
      s_Ht[tid] = (h0 + h1) + (h2 + h3);
    }
    if (need_x) bn++;
    if (t >= 29) __syncthreads();  // F: only needed before pred P0 reads s_Ht
  }
}

extern "C" void kernel_launch(void* const* d_in, const int* in_sizes, int n_in,
                              void* d_out, int out_size, void* d_ws, size_t ws_size,
                              hipStream_t stream) {
  const float* img    = (const float*)d_in[0];
  const float* tabs   = (const float*)d_in[1];
  const float* trel   = (const float*)d_in[2];
  const float* tstep  = (const float*)d_in[3];
  const float* nabs   = (const float*)d_in[4];
  const float* nstep  = (const float*)d_in[6];
  const int*   thist  = (const int*)d_in[7];
  const int*   nhist  = (const int*)d_in[8];
  const float* W_disp = (const float*)d_in[9];
  const float* b_disp = (const float*)d_in[10];
  const float* Wih_t  = (const float*)d_in[11];
  const float* Whh_t  = (const float*)d_in[12];
  const float* bih_t  = (const float*)d_in[13];
  const float* bhh_t  = (const float*)d_in[14];
  const float* Wih_n  = (const float*)d_in[15];
  const float* Whh_n  = (const float*)d_in[16];
  const float* bih_n  = (const float*)d_in[17];
  const float* bhh_n  = (const float*)d_in[18];
  const float* W_att_t = (const float*)d_in[19];
  const float* b_att_t = (const float*)d_in[20];
  const float* W_att_n = (const float*)d_in[21];
  const float* b_att_n = (const float*)d_in[22];
  const float* W_pred  = (const float*)d_in[23];
  const float* b_pred  = (const float*)d_in[24];

  char* ws = (char*)d_ws;
  f16*      Wn      = (f16*)(ws);              // 589824 B (9-unit layout)
  f16*      Wt      = (f16*)(ws + 655360);     // 196608 B
  float*    bias_n  = (float*)(ws + 851968);
  float*    bias_t  = (float*)(ws + 856064);
  int*      gt_arr  = (int*)(ws + 858112);
  int*      gn_arr  = (int*)(ws + 858304);
  float*    cn_arr  = (float*)(ws + 858496);
  int*      last29p = (int*)(ws + 859648);
  unsigned* flags   = (unsigned*)(ws + 860160);
  float*    Ptv     = (float*)(ws + 901120);      // 3*512 f32 = 6144 B
  unsigned* Hglob   = (unsigned*)(ws + 1048576);  // 3145728 B
  float*    Tglob   = (float*)(ws + 4194304);     // 131072 B

  prep_kernel<<<64, 512, 0, stream>>>(Wih_n, Whh_n, bih_n, bhh_n, Wih_t, Whh_t,
                                      bih_t, bhh_t, W_disp, b_disp,
                                      thist, nhist, Wn, Wt, Ptv,
                                      bias_n, bias_t, gt_arr, gn_arr, cn_arr,
                                      last29p, flags);
  model_kernel<<<2 * NT, 512, 0, stream>>>(img, tabs, trel, tstep, nabs, nstep,
                                           thist, nhist,
                                           W_att_t, b_att_t, W_att_n, b_att_n,
                                           W_pred, b_pred,
                                           Wn, Wt, Ptv, bias_n, bias_t,
                                           gt_arr, gn_arr, cn_arr, last29p,
                                           flags, Hglob, Tglob,
                                           (float*)d_out);
}